// Round 6
// baseline (222.862 us; speedup 1.0000x reference)
//
#include <hip/hip_runtime.h>

typedef unsigned short u16;
typedef unsigned int u32;
typedef __bf16 bf16x8 __attribute__((ext_vector_type(8)));
typedef float f32x4 __attribute__((ext_vector_type(4)));
typedef float f32x16 __attribute__((ext_vector_type(16)));
typedef u16 u16x4 __attribute__((ext_vector_type(4)));

#define GL2LDS16(g, l)                                                         \
    __builtin_amdgcn_global_load_lds(                                          \
        (__attribute__((address_space(1))) const void*)(g),                    \
        (__attribute__((address_space(3))) void*)(l), 16, 0, 0)

#define SYNC_VM(n) asm volatile("s_waitcnt vmcnt(" #n ")\ns_barrier" ::: "memory")
#define BAR()      asm volatile("s_barrier" ::: "memory")

// ---------- helpers ----------
__device__ __forceinline__ u16 f2bf(float f) {
    union { float f; u32 u; } x; x.f = f;
    u32 r = x.u + 0x7FFFu + ((x.u >> 16) & 1u);   // RNE (no NaNs here)
    return (u16)(r >> 16);
}

// pack 2 floats -> 2 bf16 in one u32 (round-half-up; lo=f0, hi=f1)
__device__ __forceinline__ u32 pack2bf(float f0, float f1) {
    union { float f; u32 u; } a, b;
    a.f = f0; b.f = f1;
    return __builtin_amdgcn_perm(b.u + 0x8000u, a.u + 0x8000u, 0x07060302u);
}

// raw v_exp_f32 (2^x)
__device__ __forceinline__ float fast_exp2(float x) {
    float r;
    asm("v_exp_f32 %0, %1" : "=v"(r) : "v"(x));
    return r;
}

// fold softmax scale * log2(e) into Q fragments (scores then used with exp2)
__device__ __forceinline__ bf16x8 scale_frag(bf16x8 v) {
#pragma unroll
    for (int i = 0; i < 8; ++i) v[i] = (__bf16)((float)v[i] * 0.1803368801f);
    return v;
}

// ---------- fused fp32 -> bf16 convert (x | qkv | wo -> contiguous ws) ----------
__global__ __launch_bounds__(256) void convert_all_kernel(const float* __restrict__ x,
                                                          const float* __restrict__ qkv,
                                                          const float* __restrict__ wo,
                                                          u16* __restrict__ out) {
    int i = (blockIdx.x * 256 + threadIdx.x) * 4;
    const float* src;
    int off;
    if (i < 4194304)      { src = x;   off = i; }
    else if (i < 7340032) { src = qkv; off = i - 4194304; }
    else                  { src = wo;  off = i - 7340032; }
    float4 v = *(const float4*)(src + off);
    u16x4 o;
    o.x = f2bf(v.x); o.y = f2bf(v.y); o.z = f2bf(v.z); o.w = f2bf(v.w);
    *(u16x4*)(out + i) = o;
}

// ---------- GEMM: C[M,N] = A[M,K] * B[N,K]^T, bf16, double-buffered pipeline ----------
template <int TM, bool OUT_BF16, bool FUSE_VT>
__global__ __launch_bounds__(256) void gemm_bt(const u16* __restrict__ A,
                                               const u16* __restrict__ B,
                                               void* __restrict__ Cout,
                                               u16* __restrict__ VtG,
                                               int M, int N, int K) {
    constexpr int MI = TM / 32;
    __shared__ u16 As[2][TM * 32];
    __shared__ u16 Bs[2][128 * 32];
    const int tid = threadIdx.x;
    const int w = tid >> 6, lane = tid & 63, ln = lane & 15, qd = lane >> 4;
    const int wr = w >> 1, wc = w & 1;
    const int m0 = blockIdx.y * TM, n0 = blockIdx.x * 128;

    const int srow = tid >> 2, scol = (tid & 3) * 8;
    const u16* Abase = A + (size_t)(m0 + srow) * K + scol;
    const u16* Bbase = B + (size_t)(n0 + srow) * K + scol;

    f32x4 acc[MI][4] = {};
    const int nsteps = K >> 5;

#pragma unroll
    for (int it = 0; it < TM / 64; ++it)
        GL2LDS16(Abase + (size_t)(it * 64) * K, &As[0][(tid + it * 256) * 8]);
#pragma unroll
    for (int it = 0; it < 2; ++it)
        GL2LDS16(Bbase + (size_t)(it * 64) * K, &Bs[0][(tid + it * 256) * 8]);

    for (int s = 0; s < nsteps; ++s) {
        const u16* Ab = As[s & 1];
        const u16* Bb = Bs[s & 1];
        if (s + 1 < nsteps) {
            const int nk = (s + 1) << 5;
            const int nb = (s + 1) & 1;
#pragma unroll
            for (int it = 0; it < TM / 64; ++it)
                GL2LDS16(Abase + (size_t)(it * 64) * K + nk, &As[nb][(tid + it * 256) * 8]);
#pragma unroll
            for (int it = 0; it < 2; ++it)
                GL2LDS16(Bbase + (size_t)(it * 64) * K + nk, &Bs[nb][(tid + it * 256) * 8]);
            if constexpr (TM == 128) SYNC_VM(4); else SYNC_VM(3);
        } else {
            SYNC_VM(0);
        }

        bf16x8 af[MI], bfr[4];
#pragma unroll
        for (int i = 0; i < MI; ++i)
            af[i] = *(const bf16x8*)&Ab[(wr * (TM / 2) + i * 16 + ln) * 32 + qd * 8];
#pragma unroll
        for (int j = 0; j < 4; ++j)
            bfr[j] = *(const bf16x8*)&Bb[(wc * 64 + j * 16 + ln) * 32 + qd * 8];
#pragma unroll
        for (int i = 0; i < MI; ++i)
#pragma unroll
            for (int j = 0; j < 4; ++j)
                acc[i][j] = __builtin_amdgcn_mfma_f32_16x16x32_bf16(af[i], bfr[j], acc[i][j], 0, 0, 0);
        BAR();
    }

    if (FUSE_VT && n0 >= 2048) {
        const int bq = m0 >> 11;
        const int sl = (m0 & 2047) + wr * (TM / 2) + qd * 4;
#pragma unroll
        for (int i = 0; i < MI; ++i)
#pragma unroll
            for (int j = 0; j < 4; ++j) {
                int d = n0 - 2048 + wc * 64 + j * 16 + ln;
                int vrow = (bq * 16 + (d >> 6)) * 64 + (d & 63);
                u16x4 ov;
                ov.x = f2bf(acc[i][j][0]); ov.y = f2bf(acc[i][j][1]);
                ov.z = f2bf(acc[i][j][2]); ov.w = f2bf(acc[i][j][3]);
                *(u16x4*)&VtG[(size_t)vrow * 2048 + sl + i * 16] = ov;
            }
        return;
    }

#pragma unroll
    for (int i = 0; i < MI; ++i)
#pragma unroll
        for (int j = 0; j < 4; ++j)
#pragma unroll
            for (int r = 0; r < 4; ++r) {
                int row = m0 + wr * (TM / 2) + i * 16 + qd * 4 + r;
                int col = n0 + wc * 64 + j * 16 + ln;
                float v = acc[i][j][r];
                if constexpr (OUT_BF16)
                    ((u16*)Cout)[(size_t)row * N + col] = f2bf(v);
                else
                    ((float*)Cout)[(size_t)row * N + col] = v;
            }
}

// ---------- flash attention (causal): 32x32 MFMA, permuted-K, zero-shuffle P ----------
// S^T = K Q^T via mfma_32x32x16 (A=K rows=keys, B=Q cols=q): C/D col=lane&31=q,
// row=(r&3)+8*(r>>2)+4*hi -> lane owns its q's scores; softmax lane-local.
// KEY TRICK (replaces R5's permlane butterfly, whose direction was wrong):
// K rows are staged into LDS PRE-PERMUTED by rho = swap(bit2,bit3) of the row
// index (free: global_load_lds takes a per-lane SOURCE address). Then the P
// values in plain register-concat order {wk[2f],wk[2f+1]} land exactly at
// B-frag key order key=16f+8*hi+j, which natural-order V^T consumes:
//   reg j <-> r=8f+4(j>>2)+(j&3) <-> rowidx=16f+8(j>>2)+4hi+(j&3);
//   rho(rowidx)=16f+8hi+j.  No cross-lane ops, no P LDS traffic.
// Causal mask uses permuted key identity:
//   key = c*64+kb*32+(r&3)+4*((r>>2)&1)+8*hi+16*(r>>3).
// Work split: block = pair (t,63-t) of 32-q tiles; waves {0,1}=heavy,
// {2,3}=light; within a pair, waves split key chunks by parity (no-max exp2
// softmax => disjoint-key partials add; combined once via LDS scratch).
// Uniform 33 wave-chunks/block, 1024 blocks. LDS 32KB.
__global__ __launch_bounds__(256) void attn_kernel(const u16* __restrict__ QKV,
                                                   const u16* __restrict__ VtG,
                                                   u16* __restrict__ AO) {
    __shared__ u16 Ks[2][64 * 64];     // [key(rho-permuted)][dh], swizzled; reused as f32 scratch
    __shared__ u16 Vts[2][64 * 64];    // [dh][key natural], swizzled; reused for l scratch

    const int tid = threadIdx.x;
    const int w = tid >> 6, lane = tid & 63;
    const int q = lane & 31, hi = lane >> 5, swz = q & 7;
    const int b = blockIdx.z, h = blockIdx.y;
    const int t = blockIdx.x;              // pair index 0..31
    const int tile = (w < 2) ? (63 - t) : t;
    const int myq = tile * 32 + q;
    const int bh = b * 16 + h;
    const int nchH = ((63 - t) >> 1) + 1;  // 17..32
    const int mynch = (tile >> 1) + 1;     // this wave's tile chunk count
    const int par = (w ^ (h >> 3) ^ b) & 1;   // key-chunk parity this wave computes

    // staging: LDS slot row = sr0 (0..31), XOR-swizzled source colgroup.
    // K source row is rho(sr0): swap bits 2<->3 (within each 16-row block).
    const int sr0 = tid >> 3;
    const int srP = (sr0 & 19) | ((sr0 & 4) << 1) | ((sr0 & 8) >> 1);
    const int sg = (tid & 7) ^ (sr0 & 7);
    const u16* ksrc = QKV + (size_t)(b * 2048 + srP) * 3072 + 1024 + h * 64 + sg * 8;
    const u16* vsrc = VtG + (size_t)(bh * 64 + sr0) * 2048 + sg * 8;

    GL2LDS16(ksrc, &Ks[0][tid * 8]);
    GL2LDS16(ksrc + (size_t)32 * 3072, &Ks[0][tid * 8 + 2048]);
    GL2LDS16(vsrc, &Vts[0][tid * 8]);
    GL2LDS16(vsrc + (size_t)32 * 2048, &Vts[0][tid * 8 + 2048]);

    // Q B-frags (col=q=lane&31, k-elem j -> dh = ks*16 + hi*8 + j), scaled
    const u16* qp = QKV + (size_t)(b * 2048 + myq) * 3072 + h * 64;
    bf16x8 qf[4];
#pragma unroll
    for (int ks = 0; ks < 4; ++ks)
        qf[ks] = scale_frag(*(const bf16x8*)(qp + ks * 16 + hi * 8));

    f32x16 o0 = {}, o1 = {};               // O^T[dh-block][q]
    float l = 0.f;

    for (int c = 0; c < nchH; ++c) {
        if (c + 1 < nchH) {
            const int k1 = (c + 1) * 64;
            const int nb = (c + 1) & 1;
            GL2LDS16(ksrc + (size_t)k1 * 3072, &Ks[nb][tid * 8]);
            GL2LDS16(ksrc + (size_t)(k1 + 32) * 3072, &Ks[nb][tid * 8 + 2048]);
            GL2LDS16(vsrc + k1, &Vts[nb][tid * 8]);
            GL2LDS16(vsrc + k1 + 32 * 2048, &Vts[nb][tid * 8 + 2048]);
            SYNC_VM(4);
        } else {
            SYNC_VM(0);
        }

        if (((c & 1) == par) && c < mynch) {
            const u16* Kb = Ks[c & 1];
            const u16* Vb = Vts[c & 1];
            bf16x8 pa[4];                  // PV B-frags: reg j = P[q][16*slot + 8*hi + j]

#pragma unroll
            for (int kb = 0; kb < 2; ++kb) {
                // ---- S^T block: rows = permuted keys kb*32+.., cols = q ----
                f32x16 z = {};
                __builtin_amdgcn_s_setprio(1);
#pragma unroll
                for (int ks = 0; ks < 4; ++ks) {
                    bf16x8 kf = *(const bf16x8*)&Kb[(kb * 32 + q) * 64 + (((ks * 2 + hi) ^ swz) * 8)];
                    z = __builtin_amdgcn_mfma_f32_32x32x16_bf16(kf, qf[ks], z, 0, 0, 0);
                }
                __builtin_amdgcn_s_setprio(0);

                // ---- causal mask (diagonal chunk only), permuted key identity ----
                if (c == mynch - 1) {
#pragma unroll
                    for (int r = 0; r < 16; ++r) {
                        int key = c * 64 + kb * 32 + (r & 3) + 4 * ((r >> 2) & 1)
                                  + 8 * hi + 16 * (r >> 3);
                        if (key > myq) z[r] = -1e30f;
                    }
                }

                // ---- exp2 + direct bf16 pack into PV frags (no cross-lane) ----
#pragma unroll
                for (int r = 0; r < 16; ++r) {
                    float p = fast_exp2(z[r]);
                    l += p;
                    pa[kb * 2 + (r >> 3)][4 * ((r >> 2) & 1) + (r & 3)] = (__bf16)p;
                }
            }

            // ---- PV: o^T[dh][q] += V^T frag x P frag (natural key order) ----
            __builtin_amdgcn_s_setprio(1);
#pragma unroll
            for (int ks = 0; ks < 4; ++ks) {
                bf16x8 vf0 = *(const bf16x8*)&Vb[q * 64 + (((ks * 2 + hi) ^ swz) * 8)];
                bf16x8 vf1 = *(const bf16x8*)&Vb[(32 + q) * 64 + (((ks * 2 + hi) ^ swz) * 8)];
                o0 = __builtin_amdgcn_mfma_f32_32x32x16_bf16(vf0, pa[ks], o0, 0, 0, 0);
                o1 = __builtin_amdgcn_mfma_f32_32x32x16_bf16(vf1, pa[ks], o1, 0, 0, 0);
            }
            __builtin_amdgcn_s_setprio(0);
        }
        BAR();
    }

    // ---- combine parity partners (o,l add; no-max softmax => no rescale) ----
    l += __shfl_xor(l, 32);
    float* scrO = (float*)&Ks[0][0];       // 2 slots x 64 lanes x 32 f32 = 16KB
    float* scrL = (float*)&Vts[0][0];
    const int slot = w >> 1;               // 0 = heavy pair, 1 = light pair
    if (par == 1) {
#pragma unroll
        for (int j = 0; j < 4; ++j) {
            f32x4 s0 = {o0[4 * j + 0], o0[4 * j + 1], o0[4 * j + 2], o0[4 * j + 3]};
            *(f32x4*)&scrO[slot * 2048 + lane * 32 + ((j ^ (lane & 7)) * 4)] = s0;
            f32x4 s1 = {o1[4 * j + 0], o1[4 * j + 1], o1[4 * j + 2], o1[4 * j + 3]};
            *(f32x4*)&scrO[slot * 2048 + lane * 32 + (((j + 4) ^ (lane & 7)) * 4)] = s1;
        }
        scrL[slot * 64 + lane] = l;
    }
    BAR();
    if (par == 0) {
        l += scrL[slot * 64 + lane];
        float inv = 1.0f / l;
#pragma unroll
        for (int j = 0; j < 4; ++j) {
            f32x4 s0 = *(const f32x4*)&scrO[slot * 2048 + lane * 32 + ((j ^ (lane & 7)) * 4)];
            f32x4 s1 = *(const f32x4*)&scrO[slot * 2048 + lane * 32 + (((j + 4) ^ (lane & 7)) * 4)];
            uint2 ov0 = {pack2bf((o0[4 * j + 0] + s0.x) * inv, (o0[4 * j + 1] + s0.y) * inv),
                         pack2bf((o0[4 * j + 2] + s0.z) * inv, (o0[4 * j + 3] + s0.w) * inv)};
            *(uint2*)&AO[(size_t)(b * 2048 + myq) * 1024 + h * 64 + 8 * j + 4 * hi] = ov0;
            uint2 ov1 = {pack2bf((o1[4 * j + 0] + s1.x) * inv, (o1[4 * j + 1] + s1.y) * inv),
                         pack2bf((o1[4 * j + 2] + s1.z) * inv, (o1[4 * j + 3] + s1.w) * inv)};
            *(uint2*)&AO[(size_t)(b * 2048 + myq) * 1024 + h * 64 + 32 + 8 * j + 4 * hi] = ov1;
        }
    }
}

// ---------- launch ----------
extern "C" void kernel_launch(void* const* d_in, const int* in_sizes, int n_in,
                              void* d_out, int out_size, void* d_ws, size_t ws_size,
                              hipStream_t stream) {
    const float* x   = (const float*)d_in[0];   // [2,2048,1024]
    const float* qkv = (const float*)d_in[1];   // [3072,1024]
    const float* wo  = (const float*)d_in[2];   // [1024,1024]
    float* out = (float*)d_out;                 // [2,2048,1024] fp32

    char* ws = (char*)d_ws;
    u16* xb    = (u16*)(ws + 0);            //  8 MB : x bf16 [4096,1024]
    u16* qkvb  = (u16*)(ws + 8388608);      //  6 MB : qkv bf16 [3072,1024]
    u16* wob   = (u16*)(ws + 14680064);     //  2 MB : wo bf16 [1024,1024]
    u16* QKVo  = (u16*)(ws + 16777216);     // 24 MB : QKV bf16 (V-cols unwritten)
    u16* AO    = (u16*)(ws + 41943040);     //  8 MB : attn out [4096,1024]
    u16* VtG   = (u16*)(ws + 50331648);     //  8 MB : V^T [2*16*64, 2048]

    convert_all_kernel<<<8192, 256, 0, stream>>>(x, qkv, wo, xb);

    gemm_bt<128, true, true><<<dim3(24, 32), 256, 0, stream>>>(xb, qkvb, QKVo, VtG,
                                                               4096, 3072, 1024);

    attn_kernel<<<dim3(32, 16, 2), 256, 0, stream>>>(QKVo, VtG, AO);

    gemm_bt<64, false, false><<<dim3(8, 64), 256, 0, stream>>>(AO, wob, out, nullptr,
                                                               4096, 1024, 1024);
}

// Round 8
// 205.234 us; speedup vs baseline: 1.0859x; 1.0859x over previous
//
#include <hip/hip_runtime.h>

typedef unsigned short u16;
typedef unsigned int u32;
typedef __bf16 bf16x8 __attribute__((ext_vector_type(8)));
typedef float f32x4 __attribute__((ext_vector_type(4)));
typedef float f32x16 __attribute__((ext_vector_type(16)));
typedef u16 u16x4 __attribute__((ext_vector_type(4)));

#define GL2LDS16(g, l)                                                         \
    __builtin_amdgcn_global_load_lds(                                          \
        (__attribute__((address_space(1))) const void*)(g),                    \
        (__attribute__((address_space(3))) void*)(l), 16, 0, 0)

#define SYNC_VM(n) asm volatile("s_waitcnt vmcnt(" #n ")\ns_barrier" ::: "memory")
#define BAR()      asm volatile("s_barrier" ::: "memory")
// Full DS-draining barrier: required when one wave's LDS WRITES must be
// visible to another wave's reads (or before clobbering LDS another wave may
// still have outstanding ds_reads against). Bare s_barrier does NOT drain
// LDS ops (that's what __syncthreads' compiler-emitted waitcnt does) — this
// was R7's tripwire nondeterminism.
#define BAR_DS()   asm volatile("s_waitcnt lgkmcnt(0)\ns_barrier" ::: "memory")

// ---------- helpers ----------
__device__ __forceinline__ u16 f2bf(float f) {
    union { float f; u32 u; } x; x.f = f;
    u32 r = x.u + 0x7FFFu + ((x.u >> 16) & 1u);   // RNE (no NaNs here)
    return (u16)(r >> 16);
}

// pack 2 floats -> 2 bf16 in one u32 (round-half-up; lo=f0, hi=f1)
__device__ __forceinline__ u32 pack2bf(float f0, float f1) {
    union { float f; u32 u; } a, b;
    a.f = f0; b.f = f1;
    return __builtin_amdgcn_perm(b.u + 0x8000u, a.u + 0x8000u, 0x07060302u);
}

// raw v_exp_f32 (2^x)
__device__ __forceinline__ float fast_exp2(float x) {
    float r;
    asm("v_exp_f32 %0, %1" : "=v"(r) : "v"(x));
    return r;
}

// fold softmax scale * log2(e) into Q fragments (scores then used with exp2)
__device__ __forceinline__ bf16x8 scale_frag(bf16x8 v) {
#pragma unroll
    for (int i = 0; i < 8; ++i) v[i] = (__bf16)((float)v[i] * 0.1803368801f);
    return v;
}

// ---------- fused fp32 -> bf16 convert (x | qkv | wo -> contiguous ws) ----------
__global__ __launch_bounds__(256) void convert_all_kernel(const float* __restrict__ x,
                                                          const float* __restrict__ qkv,
                                                          const float* __restrict__ wo,
                                                          u16* __restrict__ out) {
    int i = (blockIdx.x * 256 + threadIdx.x) * 4;
    const float* src;
    int off;
    if (i < 4194304)      { src = x;   off = i; }
    else if (i < 7340032) { src = qkv; off = i - 4194304; }
    else                  { src = wo;  off = i - 7340032; }
    float4 v = *(const float4*)(src + off);
    u16x4 o;
    o.x = f2bf(v.x); o.y = f2bf(v.y); o.z = f2bf(v.z); o.w = f2bf(v.w);
    *(u16x4*)(out + i) = o;
}

// ---------- GEMM: C[M,N] = A[M,K] * B[N,K]^T, bf16, double-buffered pipeline ----------
template <int TM, bool OUT_BF16, bool FUSE_VT>
__global__ __launch_bounds__(256) void gemm_bt(const u16* __restrict__ A,
                                               const u16* __restrict__ B,
                                               void* __restrict__ Cout,
                                               u16* __restrict__ VtG,
                                               int M, int N, int K) {
    constexpr int MI = TM / 32;
    __shared__ u16 As[2][TM * 32];
    __shared__ u16 Bs[2][128 * 32];
    const int tid = threadIdx.x;
    const int w = tid >> 6, lane = tid & 63, ln = lane & 15, qd = lane >> 4;
    const int wr = w >> 1, wc = w & 1;
    const int m0 = blockIdx.y * TM, n0 = blockIdx.x * 128;

    const int srow = tid >> 2, scol = (tid & 3) * 8;
    const u16* Abase = A + (size_t)(m0 + srow) * K + scol;
    const u16* Bbase = B + (size_t)(n0 + srow) * K + scol;

    f32x4 acc[MI][4] = {};
    const int nsteps = K >> 5;

#pragma unroll
    for (int it = 0; it < TM / 64; ++it)
        GL2LDS16(Abase + (size_t)(it * 64) * K, &As[0][(tid + it * 256) * 8]);
#pragma unroll
    for (int it = 0; it < 2; ++it)
        GL2LDS16(Bbase + (size_t)(it * 64) * K, &Bs[0][(tid + it * 256) * 8]);

    for (int s = 0; s < nsteps; ++s) {
        const u16* Ab = As[s & 1];
        const u16* Bb = Bs[s & 1];
        if (s + 1 < nsteps) {
            const int nk = (s + 1) << 5;
            const int nb = (s + 1) & 1;
#pragma unroll
            for (int it = 0; it < TM / 64; ++it)
                GL2LDS16(Abase + (size_t)(it * 64) * K + nk, &As[nb][(tid + it * 256) * 8]);
#pragma unroll
            for (int it = 0; it < 2; ++it)
                GL2LDS16(Bbase + (size_t)(it * 64) * K + nk, &Bs[nb][(tid + it * 256) * 8]);
            if constexpr (TM == 128) SYNC_VM(4); else SYNC_VM(3);
        } else {
            SYNC_VM(0);
        }

        bf16x8 af[MI], bfr[4];
#pragma unroll
        for (int i = 0; i < MI; ++i)
            af[i] = *(const bf16x8*)&Ab[(wr * (TM / 2) + i * 16 + ln) * 32 + qd * 8];
#pragma unroll
        for (int j = 0; j < 4; ++j)
            bfr[j] = *(const bf16x8*)&Bb[(wc * 64 + j * 16 + ln) * 32 + qd * 8];
#pragma unroll
        for (int i = 0; i < MI; ++i)
#pragma unroll
            for (int j = 0; j < 4; ++j)
                acc[i][j] = __builtin_amdgcn_mfma_f32_16x16x32_bf16(af[i], bfr[j], acc[i][j], 0, 0, 0);
        BAR();
    }

    if (FUSE_VT && n0 >= 2048) {
        const int bq = m0 >> 11;
        const int sl = (m0 & 2047) + wr * (TM / 2) + qd * 4;
#pragma unroll
        for (int i = 0; i < MI; ++i)
#pragma unroll
            for (int j = 0; j < 4; ++j) {
                int d = n0 - 2048 + wc * 64 + j * 16 + ln;
                int vrow = (bq * 16 + (d >> 6)) * 64 + (d & 63);
                u16x4 ov;
                ov.x = f2bf(acc[i][j][0]); ov.y = f2bf(acc[i][j][1]);
                ov.z = f2bf(acc[i][j][2]); ov.w = f2bf(acc[i][j][3]);
                *(u16x4*)&VtG[(size_t)vrow * 2048 + sl + i * 16] = ov;
            }
        return;
    }

#pragma unroll
    for (int i = 0; i < MI; ++i)
#pragma unroll
        for (int j = 0; j < 4; ++j)
#pragma unroll
            for (int r = 0; r < 4; ++r) {
                int row = m0 + wr * (TM / 2) + i * 16 + qd * 4 + r;
                int col = n0 + wc * 64 + j * 16 + ln;
                float v = acc[i][j][r];
                if constexpr (OUT_BF16)
                    ((u16*)Cout)[(size_t)row * N + col] = f2bf(v);
                else
                    ((float*)Cout)[(size_t)row * N + col] = v;
            }
}

// ---------- flash attention (causal): 32x32 MFMA, permuted-K, KEY-HALF split ----------
// Structure identical to R7 (verified-correct math; R6 verified the
// zero-shuffle machinery, R7 fixed wave activity via the key-half split).
// R8 fix: the epilogue LDS scratch handoff (scrO/scrL overlay Ks/Vts) now uses
// BAR_DS() — s_waitcnt lgkmcnt(0) + s_barrier — on BOTH sides:
//   1) before scratch writes: drains all waves' outstanding ds_reads of K/V
//      (WAR vs clobbering Ks region), 2) before scratch reads: drains the
//      writer's ds_writes (RAW visibility). Bare s_barrier drains neither —
//      that was R7's run-to-run nondeterminism (tripwire).
__global__ __launch_bounds__(256) void attn_kernel(const u16* __restrict__ QKV,
                                                   const u16* __restrict__ VtG,
                                                   u16* __restrict__ AO) {
    __shared__ u16 Ks[2][64 * 64];     // [key(rho-permuted)][dh], swizzled; reused as f32 scratch
    __shared__ u16 Vts[2][64 * 64];    // [dh][key natural], swizzled; reused for l scratch

    const int tid = threadIdx.x;
    const int w = tid >> 6, lane = tid & 63;
    const int q = lane & 31, hi = lane >> 5;
    const int fsw = ((q >> 2) ^ q) & 7;    // f(row) for rows == q (mod 32); f(r+32)=f(r)
    const int b = blockIdx.z, h = blockIdx.y;
    const int t = blockIdx.x;              // pair index 0..31 (heavy-first order)
    const int tile = (w < 2) ? (63 - t) : t;
    const int kh = w & 1;                  // 32-key half this wave owns
    const int myq = tile * 32 + q;
    const int bh = b * 16 + h;
    const int nchH = ((63 - t) >> 1) + 1;  // 17..32
    const int mynch = (tile >> 1) + 1;     // this wave's tile chunk count

    // staging: LDS slot row = sr0 (0..31 per instr), swizzled source colgroup.
    // K source row is rho(sr0) = swap bits 2<->3; f applies to the LDS row.
    const int sr0 = tid >> 3;
    const int srP = (sr0 & 19) | ((sr0 & 4) << 1) | ((sr0 & 8) >> 1);
    const int sg = (tid & 7) ^ (((sr0 >> 2) ^ sr0) & 7);
    const u16* ksrc = QKV + (size_t)(b * 2048 + srP) * 3072 + 1024 + h * 64 + sg * 8;
    const u16* vsrc = VtG + (size_t)(bh * 64 + sr0) * 2048 + sg * 8;

    GL2LDS16(ksrc, &Ks[0][tid * 8]);
    GL2LDS16(ksrc + (size_t)32 * 3072, &Ks[0][tid * 8 + 2048]);
    GL2LDS16(vsrc, &Vts[0][tid * 8]);
    GL2LDS16(vsrc + (size_t)32 * 2048, &Vts[0][tid * 8 + 2048]);

    // Q B-frags (col=q=lane&31, k-elem j -> dh = ks*16 + hi*8 + j), scaled
    const u16* qp = QKV + (size_t)(b * 2048 + myq) * 3072 + h * 64;
    bf16x8 qf[4];
#pragma unroll
    for (int ks = 0; ks < 4; ++ks)
        qf[ks] = scale_frag(*(const bf16x8*)(qp + ks * 16 + hi * 8));

    f32x16 o0 = {}, o1 = {};               // O^T[dh-block][q], partial over this key half
    float l = 0.f;

    for (int c = 0; c < nchH; ++c) {
        if (c + 1 < nchH) {
            const int k1 = (c + 1) * 64;
            const int nb = (c + 1) & 1;
            GL2LDS16(ksrc + (size_t)k1 * 3072, &Ks[nb][tid * 8]);
            GL2LDS16(ksrc + (size_t)(k1 + 32) * 3072, &Ks[nb][tid * 8 + 2048]);
            GL2LDS16(vsrc + k1, &Vts[nb][tid * 8]);
            GL2LDS16(vsrc + k1 + 32 * 2048, &Vts[nb][tid * 8 + 2048]);
            SYNC_VM(4);
        } else {
            SYNC_VM(0);
        }

        if (c < mynch) {
            const u16* Kb = Ks[c & 1];
            const u16* Vb = Vts[c & 1];

            // ---- S^T: rows = permuted keys kh*32+q, accumulate over dh ----
            f32x16 z = {};
            __builtin_amdgcn_s_setprio(1);
#pragma unroll
            for (int ks = 0; ks < 4; ++ks) {
                bf16x8 kf = *(const bf16x8*)&Kb[(kh * 32 + q) * 64 + (((ks * 2 + hi) ^ fsw) * 8)];
                z = __builtin_amdgcn_mfma_f32_32x32x16_bf16(kf, qf[ks], z, 0, 0, 0);
            }
            __builtin_amdgcn_s_setprio(0);

            // ---- causal mask (diagonal chunk only), permuted key identity ----
            if (c == mynch - 1) {
#pragma unroll
                for (int r = 0; r < 16; ++r) {
                    int key = c * 64 + kh * 32 + (r & 3) + 4 * ((r >> 2) & 1)
                              + 8 * hi + 16 * (r >> 3);
                    if (key > myq) z[r] = -1e30f;
                }
            }

            // ---- exp2 + direct bf16 pack into PV B-frags (no cross-lane) ----
            bf16x8 pa[2];
#pragma unroll
            for (int r = 0; r < 16; ++r) {
                float p = fast_exp2(z[r]);
                l += p;
                pa[r >> 3][4 * ((r >> 2) & 1) + (r & 3)] = (__bf16)p;
            }

            // ---- PV: o^T[dh][q] += V^T frag x P frag (key slots of this half) ----
            __builtin_amdgcn_s_setprio(1);
#pragma unroll
            for (int f = 0; f < 2; ++f) {
                const int cg = (kh * 2 + f) * 2 + hi;
                bf16x8 vf0 = *(const bf16x8*)&Vb[q * 64 + ((cg ^ fsw) * 8)];
                bf16x8 vf1 = *(const bf16x8*)&Vb[(32 + q) * 64 + ((cg ^ fsw) * 8)];
                o0 = __builtin_amdgcn_mfma_f32_32x32x16_bf16(vf0, pa[f], o0, 0, 0, 0);
                o1 = __builtin_amdgcn_mfma_f32_32x32x16_bf16(vf1, pa[f], o1, 0, 0, 0);
            }
            __builtin_amdgcn_s_setprio(0);
        }
        BAR();
    }

    // ---- combine key-half partners (o,l add; no-max softmax => no rescale) ----
    // BAR_DS #1: drain ALL waves' outstanding ds ops before clobbering the
    // Ks/Vts region with scratch writes (WAR vs pending K/V ds_reads).
    BAR_DS();
    l += __shfl_xor(l, 32);
    float* scrO = (float*)&Ks[0][0];       // 2 slots x 64 lanes x 32 f32 = 16KB
    float* scrL = (float*)&Vts[0][0];
    const int slot = w >> 1;               // 0 = heavy pair, 1 = light pair
    if (kh == 1) {
#pragma unroll
        for (int j = 0; j < 4; ++j) {
            f32x4 s0 = {o0[4 * j + 0], o0[4 * j + 1], o0[4 * j + 2], o0[4 * j + 3]};
            *(f32x4*)&scrO[slot * 2048 + lane * 32 + ((j ^ (lane & 7)) * 4)] = s0;
            f32x4 s1 = {o1[4 * j + 0], o1[4 * j + 1], o1[4 * j + 2], o1[4 * j + 3]};
            *(f32x4*)&scrO[slot * 2048 + lane * 32 + (((j + 4) ^ (lane & 7)) * 4)] = s1;
        }
        scrL[slot * 64 + lane] = l;
    }
    // BAR_DS #2: writer's ds_writes must complete before partner reads (RAW).
    BAR_DS();
    if (kh == 0) {
        l += scrL[slot * 64 + lane];
        float inv = 1.0f / l;
#pragma unroll
        for (int j = 0; j < 4; ++j) {
            f32x4 s0 = *(const f32x4*)&scrO[slot * 2048 + lane * 32 + ((j ^ (lane & 7)) * 4)];
            f32x4 s1 = *(const f32x4*)&scrO[slot * 2048 + lane * 32 + (((j + 4) ^ (lane & 7)) * 4)];
            uint2 ov0 = {pack2bf((o0[4 * j + 0] + s0.x) * inv, (o0[4 * j + 1] + s0.y) * inv),
                         pack2bf((o0[4 * j + 2] + s0.z) * inv, (o0[4 * j + 3] + s0.w) * inv)};
            *(uint2*)&AO[(size_t)(b * 2048 + myq) * 1024 + h * 64 + 8 * j + 4 * hi] = ov0;
            uint2 ov1 = {pack2bf((o1[4 * j + 0] + s1.x) * inv, (o1[4 * j + 1] + s1.y) * inv),
                         pack2bf((o1[4 * j + 2] + s1.z) * inv, (o1[4 * j + 3] + s1.w) * inv)};
            *(uint2*)&AO[(size_t)(b * 2048 + myq) * 1024 + h * 64 + 32 + 8 * j + 4 * hi] = ov1;
        }
    }
}

// ---------- launch ----------
extern "C" void kernel_launch(void* const* d_in, const int* in_sizes, int n_in,
                              void* d_out, int out_size, void* d_ws, size_t ws_size,
                              hipStream_t stream) {
    const float* x   = (const float*)d_in[0];   // [2,2048,1024]
    const float* qkv = (const float*)d_in[1];   // [3072,1024]
    const float* wo  = (const float*)d_in[2];   // [1024,1024]
    float* out = (float*)d_out;                 // [2,2048,1024] fp32

    char* ws = (char*)d_ws;
    u16* xb    = (u16*)(ws + 0);            //  8 MB : x bf16 [4096,1024]
    u16* qkvb  = (u16*)(ws + 8388608);      //  6 MB : qkv bf16 [3072,1024]
    u16* wob   = (u16*)(ws + 14680064);     //  2 MB : wo bf16 [1024,1024]
    u16* QKVo  = (u16*)(ws + 16777216);     // 24 MB : QKV bf16 (V-cols unwritten)
    u16* AO    = (u16*)(ws + 41943040);     //  8 MB : attn out [4096,1024]
    u16* VtG   = (u16*)(ws + 50331648);     //  8 MB : V^T [2*16*64, 2048]

    convert_all_kernel<<<8192, 256, 0, stream>>>(x, qkv, wo, xb);

    gemm_bt<128, true, true><<<dim3(24, 32), 256, 0, stream>>>(xb, qkvb, QKVo, VtG,
                                                               4096, 3072, 1024);

    attn_kernel<<<dim3(32, 16, 2), 256, 0, stream>>>(QKVo, VtG, AO);

    gemm_bt<64, false, false><<<dim3(8, 64), 256, 0, stream>>>(AO, wob, out, nullptr,
                                                               4096, 1024, 1024);
}

// Round 9
// 175.253 us; speedup vs baseline: 1.2717x; 1.1711x over previous
//
#include <hip/hip_runtime.h>

typedef unsigned short u16;
typedef unsigned int u32;
typedef __bf16 bf16x8 __attribute__((ext_vector_type(8)));
typedef float f32x4 __attribute__((ext_vector_type(4)));
typedef u16 u16x4 __attribute__((ext_vector_type(4)));
typedef u16 u16x8 __attribute__((ext_vector_type(8)));

#define GL2LDS16(g, l)                                                         \
    __builtin_amdgcn_global_load_lds(                                          \
        (__attribute__((address_space(1))) const void*)(g),                    \
        (__attribute__((address_space(3))) void*)(l), 16, 0, 0)

#define SYNC_VM(n) asm volatile("s_waitcnt vmcnt(" #n ")\ns_barrier" ::: "memory")
#define BAR()      asm volatile("s_barrier" ::: "memory")
// DS-draining barrier (R7 lesson): required when one wave's LDS writes must be
// visible to another wave's reads, or before clobbering LDS others may read.
#define BAR_DS()   asm volatile("s_waitcnt lgkmcnt(0)\ns_barrier" ::: "memory")

// ---------- helpers ----------
__device__ __forceinline__ u16 f2bf(float f) {
    union { float f; u32 u; } x; x.f = f;
    u32 r = x.u + 0x7FFFu + ((x.u >> 16) & 1u);   // RNE (no NaNs here)
    return (u16)(r >> 16);
}

// pack 2 floats -> 2 bf16 in one u32 (round-half-up; lo=f0, hi=f1)
__device__ __forceinline__ u32 pack2bf(float f0, float f1) {
    union { float f; u32 u; } a, b;
    a.f = f0; b.f = f1;
    return __builtin_amdgcn_perm(b.u + 0x8000u, a.u + 0x8000u, 0x07060302u);
}

// raw v_exp_f32 (2^x)
__device__ __forceinline__ float fast_exp2(float x) {
    float r;
    asm("v_exp_f32 %0, %1" : "=v"(r) : "v"(x));
    return r;
}

// fold softmax scale * log2(e) into Q fragments (scores then used with exp2)
__device__ __forceinline__ bf16x8 scale_frag(bf16x8 v) {
#pragma unroll
    for (int i = 0; i < 8; ++i) v[i] = (__bf16)((float)v[i] * 0.1803368801f);
    return v;
}

// ---------- fused fp32 -> bf16 convert (x | qkv | wo -> contiguous ws) ----------
__global__ __launch_bounds__(256) void convert_all_kernel(const float* __restrict__ x,
                                                          const float* __restrict__ qkv,
                                                          const float* __restrict__ wo,
                                                          u16* __restrict__ out) {
    int i = (blockIdx.x * 256 + threadIdx.x) * 4;
    const float* src;
    int off;
    if (i < 4194304)      { src = x;   off = i; }
    else if (i < 7340032) { src = qkv; off = i - 4194304; }
    else                  { src = wo;  off = i - 7340032; }
    float4 v = *(const float4*)(src + off);
    u16x4 o;
    o.x = f2bf(v.x); o.y = f2bf(v.y); o.z = f2bf(v.z); o.w = f2bf(v.w);
    *(u16x4*)(out + i) = o;
}

// ---------- GEMM: C[M,N] = A[M,K] * B[N,K]^T, bf16, double-buffered pipeline ----------
// FUSE_VT: blocks with n0 >= 2048 (V columns of the QKV projection) write ONLY
// the transposed copy VtG[(b*16+h)*64+dh][s]. R9: that store now goes through
// an LDS transpose (reusing the staging buffer) so global stores are 256B
// coalesced u16x8 along s, instead of 8B x 4KB-stride scatter (~4x write amp).
template <int TM, bool OUT_BF16, bool FUSE_VT>
__global__ __launch_bounds__(256) void gemm_bt(const u16* __restrict__ A,
                                               const u16* __restrict__ B,
                                               void* __restrict__ Cout,
                                               u16* __restrict__ VtG,
                                               int M, int N, int K) {
    constexpr int MI = TM / 32;
    // single LDS pool: As = SM[0 .. 2*TM*32), Bs = SM[2*TM*32 ..).
    // For TM=128 the pool is exactly 32KB = the 128x128 bf16 epilogue tile.
    __shared__ u16 SM[2 * TM * 32 + 2 * 128 * 32];
    u16* Asm = SM;
    u16* Bsm = SM + 2 * TM * 32;
    const int tid = threadIdx.x;
    const int w = tid >> 6, lane = tid & 63, ln = lane & 15, qd = lane >> 4;
    const int wr = w >> 1, wc = w & 1;
    const int m0 = blockIdx.y * TM, n0 = blockIdx.x * 128;

    const int srow = tid >> 2, scol = (tid & 3) * 8;
    const u16* Abase = A + (size_t)(m0 + srow) * K + scol;
    const u16* Bbase = B + (size_t)(n0 + srow) * K + scol;

    f32x4 acc[MI][4] = {};
    const int nsteps = K >> 5;

#pragma unroll
    for (int it = 0; it < TM / 64; ++it)
        GL2LDS16(Abase + (size_t)(it * 64) * K, &Asm[(tid + it * 256) * 8]);
#pragma unroll
    for (int it = 0; it < 2; ++it)
        GL2LDS16(Bbase + (size_t)(it * 64) * K, &Bsm[(tid + it * 256) * 8]);

    for (int s = 0; s < nsteps; ++s) {
        const u16* Ab = &Asm[(s & 1) * TM * 32];
        const u16* Bb = &Bsm[(s & 1) * 128 * 32];
        if (s + 1 < nsteps) {
            const int nk = (s + 1) << 5;
            const int nb = (s + 1) & 1;
#pragma unroll
            for (int it = 0; it < TM / 64; ++it)
                GL2LDS16(Abase + (size_t)(it * 64) * K + nk, &Asm[nb * TM * 32 + (tid + it * 256) * 8]);
#pragma unroll
            for (int it = 0; it < 2; ++it)
                GL2LDS16(Bbase + (size_t)(it * 64) * K + nk, &Bsm[nb * 128 * 32 + (tid + it * 256) * 8]);
            if constexpr (TM == 128) SYNC_VM(4); else SYNC_VM(3);
        } else {
            SYNC_VM(0);
        }

        bf16x8 af[MI], bfr[4];
#pragma unroll
        for (int i = 0; i < MI; ++i)
            af[i] = *(const bf16x8*)&Ab[(wr * (TM / 2) + i * 16 + ln) * 32 + qd * 8];
#pragma unroll
        for (int j = 0; j < 4; ++j)
            bfr[j] = *(const bf16x8*)&Bb[(wc * 64 + j * 16 + ln) * 32 + qd * 8];
        __builtin_amdgcn_s_setprio(1);
#pragma unroll
        for (int i = 0; i < MI; ++i)
#pragma unroll
            for (int j = 0; j < 4; ++j)
                acc[i][j] = __builtin_amdgcn_mfma_f32_16x16x32_bf16(af[i], bfr[j], acc[i][j], 0, 0, 0);
        __builtin_amdgcn_s_setprio(0);
        BAR();
    }

    if constexpr (FUSE_VT) {
        if (n0 >= 2048) {
            // ---- LDS-transpose epilogue for coalesced VtG stores ----
            // SM[c][r ^ xorv(c)] holds C[m0+r][n0+c] as bf16; xorv(c) =
            // ((c>>2)&3)<<4 is wave-uniform on the read side (<=2-way banks)
            // and spreads the write side across banks (4-way, 16 instrs only).
            const int bq = m0 >> 11;
            BAR_DS();                      // drain all ds_reads of staging data
#pragma unroll
            for (int i = 0; i < MI; ++i)
#pragma unroll
                for (int j = 0; j < 4; ++j) {
                    int col = wc * 64 + j * 16 + ln;
                    int row0 = wr * 64 + i * 16 + qd * 4;
                    int pr = row0 ^ (((col >> 2) & 3) << 4);
                    u16x4 ov;
                    ov.x = f2bf(acc[i][j][0]); ov.y = f2bf(acc[i][j][1]);
                    ov.z = f2bf(acc[i][j][2]); ov.w = f2bf(acc[i][j][3]);
                    *(u16x4*)&SM[col * 128 + pr] = ov;
                }
            BAR_DS();                      // writes visible before cross-wave reads
#pragma unroll
            for (int p = 0; p < 8; ++p) {
                int flat = p * 2048 + tid * 8;
                int colL = flat >> 7, rowL = flat & 127;
                int pr = rowL ^ (((colL >> 2) & 3) << 4);
                u16x8 v = *(const u16x8*)&SM[colL * 128 + pr];
                int d = n0 - 2048 + colL;
                int vrow = (bq * 16 + (d >> 6)) * 64 + (d & 63);
                *(u16x8*)&VtG[(size_t)vrow * 2048 + (m0 & 2047) + rowL] = v;
            }
            return;
        }
    }

#pragma unroll
    for (int i = 0; i < MI; ++i)
#pragma unroll
        for (int j = 0; j < 4; ++j)
#pragma unroll
            for (int r = 0; r < 4; ++r) {
                int row = m0 + wr * (TM / 2) + i * 16 + qd * 4 + r;
                int col = n0 + wc * 64 + j * 16 + ln;
                float v = acc[i][j][r];
                if constexpr (OUT_BF16)
                    ((u16*)Cout)[(size_t)row * N + col] = f2bf(v);
                else
                    ((float*)Cout)[(size_t)row * N + col] = v;
            }
}

// ---------- flash attention (causal): R2 structure (best measured, 51us) ----------
// Uniform pairs of 32-row q-tiles (t, 63-t): waves 0-1 = heavy tile 63-t
// (active all nchH chunks), waves 2-3 = light tile t (active while c<mynch).
// nchH+nchL = 33 for every t -> uniform block work, 1024 blocks, 40KiB LDS x4
// = full 160KiB pool, 16 waves/CU. K/V staged once per block via GL2LDS,
// double-buffered, XOR-swizzled LDS; transposed scores (S^T = K Q^T); no-max
// exp2 softmax (scale*log2e folded into Q, raw v_exp_f32); per-wave P buffer
// (same-wave in-order DS); in-kernel normalization. R9 adds only T5 setprio
// around the MFMA clusters (measured +4-7% on phase-split attn).
// R5-R8 lesson: 32x32-MFMA restructures (longer dep chains, fewer independent
// MFMA chains/wave) lose to this shape even at 2.5x lower LDS traffic.
__global__ __launch_bounds__(256) void attn_kernel(const u16* __restrict__ QKV,
                                                   const u16* __restrict__ VtG,
                                                   u16* __restrict__ AO) {
    __shared__ u16 Ks[2][64 * 64];     // [key][dh], swizzled
    __shared__ u16 Vts[2][64 * 64];    // [dh][key], swizzled
    __shared__ u16 Pls[4][16 * 64];    // per wave P[q][key], swizzled

    const int tid = threadIdx.x;
    const int w = tid >> 6, lane = tid & 63, ln = lane & 15, qd = lane >> 4;
    const int b = blockIdx.z, h = blockIdx.y;
    const int t = blockIdx.x;              // pair index 0..31 (heavy-first order)
    const int tH = 63 - t, tL = t;         // 32-row q tiles
    const int tile = (w < 2) ? tH : tL;
    const int myq = tile * 32 + (w & 1) * 16 + ln;
    const int bh = b * 16 + h;
    const int swz = ln & 7;
    const int nchH = (tH >> 1) + 1;        // 17..32
    const int mynch = (tile >> 1) + 1;     // chunks this wave is active for

    // staging: slot row = tid>>3 (0..31), swizzled source colgroup
    const int sr0 = tid >> 3;
    const int sg = (tid & 7) ^ (sr0 & 7);
    const u16* ksrc = QKV + (size_t)(b * 2048 + sr0) * 3072 + 1024 + h * 64 + sg * 8;
    const u16* vsrc = VtG + (size_t)(bh * 64 + sr0) * 2048 + sg * 8;

    GL2LDS16(ksrc, &Ks[0][tid * 8]);
    GL2LDS16(ksrc + (size_t)32 * 3072, &Ks[0][tid * 8 + 2048]);
    GL2LDS16(vsrc, &Vts[0][tid * 8]);
    GL2LDS16(vsrc + (size_t)32 * 2048, &Vts[0][tid * 8 + 2048]);

    // Q B-frags, scale*log2e folded in
    const u16* qp = QKV + (size_t)(b * 2048 + myq) * 3072 + h * 64;
    bf16x8 qf0 = scale_frag(*(const bf16x8*)(qp + qd * 8));
    bf16x8 qf1 = scale_frag(*(const bf16x8*)(qp + 32 + qd * 8));

    f32x4 o[4] = {};
    float l = 0.f;
    u16* Pw = Pls[w];

    for (int c = 0; c < nchH; ++c) {
        if (c + 1 < nchH) {
            const int k1 = (c + 1) * 64;
            const int nb = (c + 1) & 1;
            GL2LDS16(ksrc + (size_t)k1 * 3072, &Ks[nb][tid * 8]);
            GL2LDS16(ksrc + (size_t)(k1 + 32) * 3072, &Ks[nb][tid * 8 + 2048]);
            GL2LDS16(vsrc + k1, &Vts[nb][tid * 8]);
            GL2LDS16(vsrc + k1 + 32 * 2048, &Vts[nb][tid * 8 + 2048]);
            SYNC_VM(4);
        } else {
            SYNC_VM(0);
        }

        if (c < mynch) {
            const u16* Kb = Ks[c & 1];
            const u16* Vb = Vts[c & 1];

            // ---- S^T = K Q^T ----
            f32x4 s[4];
            __builtin_amdgcn_s_setprio(1);
#pragma unroll
            for (int kt = 0; kt < 4; ++kt) {
                const u16* kr = Kb + (kt * 16 + ln) * 64;
                bf16x8 kf0 = *(const bf16x8*)(kr + ((qd ^ swz) * 8));
                bf16x8 kf1 = *(const bf16x8*)(kr + (((qd + 4) ^ swz) * 8));
                f32x4 z = {0.f, 0.f, 0.f, 0.f};
                z = __builtin_amdgcn_mfma_f32_16x16x32_bf16(kf0, qf0, z, 0, 0, 0);
                z = __builtin_amdgcn_mfma_f32_16x16x32_bf16(kf1, qf1, z, 0, 0, 0);
                s[kt] = z;
            }
            __builtin_amdgcn_s_setprio(0);

            // ---- mask (diagonal chunk only) + exp2 + pack to LDS ----
            if (c == mynch - 1) {
#pragma unroll
                for (int kt = 0; kt < 4; ++kt)
#pragma unroll
                    for (int r = 0; r < 4; ++r) {
                        int key = c * 64 + kt * 16 + qd * 4 + r;
                        if (key > myq) s[kt][r] = -1e30f;
                    }
            }
#pragma unroll
            for (int kt = 0; kt < 4; ++kt) {
                float p0 = fast_exp2(s[kt][0]), p1 = fast_exp2(s[kt][1]);
                float p2 = fast_exp2(s[kt][2]), p3 = fast_exp2(s[kt][3]);
                l += (p0 + p1) + (p2 + p3);
                uint2 pk = {pack2bf(p0, p1), pack2bf(p2, p3)};
                int g = kt * 2 + (qd >> 1);
                *(uint2*)&Pw[ln * 64 + ((g ^ swz) * 8) + (qd & 1) * 4] = pk;
            }
            bf16x8 pf0 = *(const bf16x8*)&Pw[ln * 64 + ((qd ^ swz) * 8)];
            bf16x8 pf1 = *(const bf16x8*)&Pw[ln * 64 + (((qd + 4) ^ swz) * 8)];

            // ---- PV ----
            __builtin_amdgcn_s_setprio(1);
#pragma unroll
            for (int dt = 0; dt < 4; ++dt) {
                const u16* vr = Vb + (dt * 16 + ln) * 64;
                bf16x8 vf0 = *(const bf16x8*)(vr + ((qd ^ swz) * 8));
                bf16x8 vf1 = *(const bf16x8*)(vr + (((qd + 4) ^ swz) * 8));
                o[dt] = __builtin_amdgcn_mfma_f32_16x16x32_bf16(vf0, pf0, o[dt], 0, 0, 0);
                o[dt] = __builtin_amdgcn_mfma_f32_16x16x32_bf16(vf1, pf1, o[dt], 0, 0, 0);
            }
            __builtin_amdgcn_s_setprio(0);
        }
        BAR();
    }

    // ---- deferred l reduction, normalize, packed stores ----
    l += __shfl_xor(l, 16); l += __shfl_xor(l, 32);
    float inv = 1.0f / l;
#pragma unroll
    for (int dt = 0; dt < 4; ++dt) {
        uint2 ov = {pack2bf(o[dt][0] * inv, o[dt][1] * inv),
                    pack2bf(o[dt][2] * inv, o[dt][3] * inv)};
        *(uint2*)&AO[(size_t)(b * 2048 + myq) * 1024 + h * 64 + dt * 16 + qd * 4] = ov;
    }
}

// ---------- launch ----------
extern "C" void kernel_launch(void* const* d_in, const int* in_sizes, int n_in,
                              void* d_out, int out_size, void* d_ws, size_t ws_size,
                              hipStream_t stream) {
    const float* x   = (const float*)d_in[0];   // [2,2048,1024]
    const float* qkv = (const float*)d_in[1];   // [3072,1024]
    const float* wo  = (const float*)d_in[2];   // [1024,1024]
    float* out = (float*)d_out;                 // [2,2048,1024] fp32

    char* ws = (char*)d_ws;
    u16* xb    = (u16*)(ws + 0);            //  8 MB : x bf16 [4096,1024]
    u16* qkvb  = (u16*)(ws + 8388608);      //  6 MB : qkv bf16 [3072,1024]
    u16* wob   = (u16*)(ws + 14680064);     //  2 MB : wo bf16 [1024,1024]
    u16* QKVo  = (u16*)(ws + 16777216);     // 24 MB : QKV bf16 (V-cols unwritten)
    u16* AO    = (u16*)(ws + 41943040);     //  8 MB : attn out [4096,1024]
    u16* VtG   = (u16*)(ws + 50331648);     //  8 MB : V^T [2*16*64, 2048]

    convert_all_kernel<<<8192, 256, 0, stream>>>(x, qkv, wo, xb);

    gemm_bt<128, true, true><<<dim3(24, 32), 256, 0, stream>>>(xb, qkvb, QKVo, VtG,
                                                               4096, 3072, 1024);

    attn_kernel<<<dim3(32, 16, 2), 256, 0, stream>>>(QKVo, VtG, AO);

    gemm_bt<64, false, false><<<dim3(8, 64), 256, 0, stream>>>(AO, wob, out, nullptr,
                                                               4096, 1024, 1024);
}

// Round 10
// 174.293 us; speedup vs baseline: 1.2787x; 1.0055x over previous
//
#include <hip/hip_runtime.h>

typedef unsigned short u16;
typedef unsigned int u32;
typedef __bf16 bf16x8 __attribute__((ext_vector_type(8)));
typedef float f32x4 __attribute__((ext_vector_type(4)));
typedef u16 u16x4 __attribute__((ext_vector_type(4)));
typedef u16 u16x8 __attribute__((ext_vector_type(8)));

#define GL2LDS16(g, l)                                                         \
    __builtin_amdgcn_global_load_lds(                                          \
        (__attribute__((address_space(1))) const void*)(g),                    \
        (__attribute__((address_space(3))) void*)(l), 16, 0, 0)

#define SYNC_VM(n) asm volatile("s_waitcnt vmcnt(" #n ")\ns_barrier" ::: "memory")
#define BAR()      asm volatile("s_barrier" ::: "memory")
// DS-draining barrier (R7 lesson): required when one wave's LDS writes must be
// visible to another wave's reads, or before clobbering LDS others may read.
#define BAR_DS()   asm volatile("s_waitcnt lgkmcnt(0)\ns_barrier" ::: "memory")

// ---------- helpers ----------
__device__ __forceinline__ u16 f2bf(float f) {
    union { float f; u32 u; } x; x.f = f;
    u32 r = x.u + 0x7FFFu + ((x.u >> 16) & 1u);   // RNE (no NaNs here)
    return (u16)(r >> 16);
}

// pack 2 floats -> 2 bf16 in one u32 (round-half-up; lo=f0, hi=f1)
__device__ __forceinline__ u32 pack2bf(float f0, float f1) {
    union { float f; u32 u; } a, b;
    a.f = f0; b.f = f1;
    return __builtin_amdgcn_perm(b.u + 0x8000u, a.u + 0x8000u, 0x07060302u);
}

// raw v_exp_f32 (2^x)
__device__ __forceinline__ float fast_exp2(float x) {
    float r;
    asm("v_exp_f32 %0, %1" : "=v"(r) : "v"(x));
    return r;
}

// fold softmax scale * log2(e) into Q fragments (scores then used with exp2)
__device__ __forceinline__ bf16x8 scale_frag(bf16x8 v) {
#pragma unroll
    for (int i = 0; i < 8; ++i) v[i] = (__bf16)((float)v[i] * 0.1803368801f);
    return v;
}

// ---------- fused fp32 -> bf16 convert (x | qkv | wo -> contiguous ws) ----------
__global__ __launch_bounds__(256) void convert_all_kernel(const float* __restrict__ x,
                                                          const float* __restrict__ qkv,
                                                          const float* __restrict__ wo,
                                                          u16* __restrict__ out) {
    int i = (blockIdx.x * 256 + threadIdx.x) * 4;
    const float* src;
    int off;
    if (i < 4194304)      { src = x;   off = i; }
    else if (i < 7340032) { src = qkv; off = i - 4194304; }
    else                  { src = wo;  off = i - 7340032; }
    float4 v = *(const float4*)(src + off);
    u16x4 o;
    o.x = f2bf(v.x); o.y = f2bf(v.y); o.z = f2bf(v.z); o.w = f2bf(v.w);
    *(u16x4*)(out + i) = o;
}

// ---------- GEMM: C[M,N] = A[M,K] * B[N,K]^T, bf16, double-buffered pipeline ----------
// FUSE_VT: blocks with n0 >= 2048 (V columns of the QKV projection) write ONLY
// the transposed copy VtG[(b*16+h)*64+dh][s], via an LDS transpose (reusing the
// staging buffer) so global stores are 256B coalesced u16x8 along s (R9 win).
template <int TM, bool OUT_BF16, bool FUSE_VT>
__global__ __launch_bounds__(256) void gemm_bt(const u16* __restrict__ A,
                                               const u16* __restrict__ B,
                                               void* __restrict__ Cout,
                                               u16* __restrict__ VtG,
                                               int M, int N, int K) {
    constexpr int MI = TM / 32;
    // single LDS pool: As = SM[0 .. 2*TM*32), Bs = SM[2*TM*32 ..).
    // For TM=128 the pool is exactly 32KB = the 128x128 bf16 epilogue tile.
    __shared__ u16 SM[2 * TM * 32 + 2 * 128 * 32];
    u16* Asm = SM;
    u16* Bsm = SM + 2 * TM * 32;
    const int tid = threadIdx.x;
    const int w = tid >> 6, lane = tid & 63, ln = lane & 15, qd = lane >> 4;
    const int wr = w >> 1, wc = w & 1;
    const int m0 = blockIdx.y * TM, n0 = blockIdx.x * 128;

    const int srow = tid >> 2, scol = (tid & 3) * 8;
    const u16* Abase = A + (size_t)(m0 + srow) * K + scol;
    const u16* Bbase = B + (size_t)(n0 + srow) * K + scol;

    f32x4 acc[MI][4] = {};
    const int nsteps = K >> 5;

#pragma unroll
    for (int it = 0; it < TM / 64; ++it)
        GL2LDS16(Abase + (size_t)(it * 64) * K, &Asm[(tid + it * 256) * 8]);
#pragma unroll
    for (int it = 0; it < 2; ++it)
        GL2LDS16(Bbase + (size_t)(it * 64) * K, &Bsm[(tid + it * 256) * 8]);

    for (int s = 0; s < nsteps; ++s) {
        const u16* Ab = &Asm[(s & 1) * TM * 32];
        const u16* Bb = &Bsm[(s & 1) * 128 * 32];
        if (s + 1 < nsteps) {
            const int nk = (s + 1) << 5;
            const int nb = (s + 1) & 1;
#pragma unroll
            for (int it = 0; it < TM / 64; ++it)
                GL2LDS16(Abase + (size_t)(it * 64) * K + nk, &Asm[nb * TM * 32 + (tid + it * 256) * 8]);
#pragma unroll
            for (int it = 0; it < 2; ++it)
                GL2LDS16(Bbase + (size_t)(it * 64) * K + nk, &Bsm[nb * 128 * 32 + (tid + it * 256) * 8]);
            if constexpr (TM == 128) SYNC_VM(4); else SYNC_VM(3);
        } else {
            SYNC_VM(0);
        }

        bf16x8 af[MI], bfr[4];
#pragma unroll
        for (int i = 0; i < MI; ++i)
            af[i] = *(const bf16x8*)&Ab[(wr * (TM / 2) + i * 16 + ln) * 32 + qd * 8];
#pragma unroll
        for (int j = 0; j < 4; ++j)
            bfr[j] = *(const bf16x8*)&Bb[(wc * 64 + j * 16 + ln) * 32 + qd * 8];
        __builtin_amdgcn_s_setprio(1);
#pragma unroll
        for (int i = 0; i < MI; ++i)
#pragma unroll
            for (int j = 0; j < 4; ++j)
                acc[i][j] = __builtin_amdgcn_mfma_f32_16x16x32_bf16(af[i], bfr[j], acc[i][j], 0, 0, 0);
        __builtin_amdgcn_s_setprio(0);
        BAR();
    }

    if constexpr (FUSE_VT) {
        if (n0 >= 2048) {
            // ---- LDS-transpose epilogue for coalesced VtG stores ----
            const int bq = m0 >> 11;
            BAR_DS();                      // drain all ds_reads of staging data
#pragma unroll
            for (int i = 0; i < MI; ++i)
#pragma unroll
                for (int j = 0; j < 4; ++j) {
                    int col = wc * 64 + j * 16 + ln;
                    int row0 = wr * 64 + i * 16 + qd * 4;
                    int pr = row0 ^ (((col >> 2) & 3) << 4);
                    u16x4 ov;
                    ov.x = f2bf(acc[i][j][0]); ov.y = f2bf(acc[i][j][1]);
                    ov.z = f2bf(acc[i][j][2]); ov.w = f2bf(acc[i][j][3]);
                    *(u16x4*)&SM[col * 128 + pr] = ov;
                }
            BAR_DS();                      // writes visible before cross-wave reads
#pragma unroll
            for (int p = 0; p < 8; ++p) {
                int flat = p * 2048 + tid * 8;
                int colL = flat >> 7, rowL = flat & 127;
                int pr = rowL ^ (((colL >> 2) & 3) << 4);
                u16x8 v = *(const u16x8*)&SM[colL * 128 + pr];
                int d = n0 - 2048 + colL;
                int vrow = (bq * 16 + (d >> 6)) * 64 + (d & 63);
                *(u16x8*)&VtG[(size_t)vrow * 2048 + (m0 & 2047) + rowL] = v;
            }
            return;
        }
    }

#pragma unroll
    for (int i = 0; i < MI; ++i)
#pragma unroll
        for (int j = 0; j < 4; ++j)
#pragma unroll
            for (int r = 0; r < 4; ++r) {
                int row = m0 + wr * (TM / 2) + i * 16 + qd * 4 + r;
                int col = n0 + wc * 64 + j * 16 + ln;
                float v = acc[i][j][r];
                if constexpr (OUT_BF16)
                    ((u16*)Cout)[(size_t)row * N + col] = f2bf(v);
                else
                    ((float*)Cout)[(size_t)row * N + col] = v;
            }
}

// ---------- flash attention (causal): R2 structure + permuted-K register P ----------
// R2/R9 base (best measured): uniform pairs (t,63-t) of 32-row q-tiles, waves
// 0-1 heavy / 2-3 light (16 q each), 1024 blocks, GL2LDS double-buffered K/V,
// XOR-swizzled LDS, transposed scores (S^T = K Q^T), no-max exp2 softmax,
// T5 setprio, in-kernel normalization.
// R10 change (mechanism verified in R6 for 32x32; re-derived for 16x16): the
// P LDS roundtrip (4 ds_write_b64 + lgkm drain + 2 ds_read_b128 per wave-epoch,
// pure latency on the critical path) is ELIMINATED by pre-permuting K rows at
// staging. Stage LDS row (h,Q1,Q0,r1,r0) [bits 4..0] from source key row
// (Q1,Q0,h,r1,r0): then lane (ln,qd)'s score regs, concatenated in kt order,
// ARE the PV B-fragment: pf0 = [exp2(s[0]),exp2(s[1])] covers keys 8qd+j of
// block 0-31, pf1 = [s[2],s[3]] keys 32-63. Causal-mask key identity becomes
//   key = c*64 + 32*(kt>>1) + 8*qd + 4*(kt&1) + r.
// V stays natural order (PV A-frag k = 8qd+j matches). LDS 40->32KB.
__global__ __launch_bounds__(256) void attn_kernel(const u16* __restrict__ QKV,
                                                   const u16* __restrict__ VtG,
                                                   u16* __restrict__ AO) {
    __shared__ u16 Ks[2][64 * 64];     // [stored-key(pi-permuted)][dh], swizzled
    __shared__ u16 Vts[2][64 * 64];    // [dh][key natural], swizzled

    const int tid = threadIdx.x;
    const int w = tid >> 6, lane = tid & 63, ln = lane & 15, qd = lane >> 4;
    const int b = blockIdx.z, h = blockIdx.y;
    const int t = blockIdx.x;              // pair index 0..31 (heavy-first order)
    const int tH = 63 - t, tL = t;         // 32-row q tiles
    const int tile = (w < 2) ? tH : tL;
    const int myq = tile * 32 + (w & 1) * 16 + ln;
    const int bh = b * 16 + h;
    const int swz = ln & 7;
    const int nchH = (tH >> 1) + 1;        // 17..32
    const int mynch = (tile >> 1) + 1;     // chunks this wave is active for

    // staging: LDS slot row = sr0 (0..31 per instr), swizzled source colgroup.
    // K source row = pi(sr0): LDS row (h,Q1,Q0,r1,r0) <- key (Q1,Q0,h,r1,r0).
    const int sr0 = tid >> 3;
    const int srP = ((sr0 >> 2) & 3) * 8 + ((sr0 >> 4) & 1) * 4 + (sr0 & 3);
    const int sg = (tid & 7) ^ (sr0 & 7);
    const u16* ksrc = QKV + (size_t)(b * 2048 + srP) * 3072 + 1024 + h * 64 + sg * 8;
    const u16* vsrc = VtG + (size_t)(bh * 64 + sr0) * 2048 + sg * 8;

    GL2LDS16(ksrc, &Ks[0][tid * 8]);
    GL2LDS16(ksrc + (size_t)32 * 3072, &Ks[0][tid * 8 + 2048]);
    GL2LDS16(vsrc, &Vts[0][tid * 8]);
    GL2LDS16(vsrc + (size_t)32 * 2048, &Vts[0][tid * 8 + 2048]);

    // Q B-frags, scale*log2e folded in
    const u16* qp = QKV + (size_t)(b * 2048 + myq) * 3072 + h * 64;
    bf16x8 qf0 = scale_frag(*(const bf16x8*)(qp + qd * 8));
    bf16x8 qf1 = scale_frag(*(const bf16x8*)(qp + 32 + qd * 8));

    f32x4 o[4] = {};
    float l = 0.f;

    for (int c = 0; c < nchH; ++c) {
        if (c + 1 < nchH) {
            const int k1 = (c + 1) * 64;
            const int nb = (c + 1) & 1;
            GL2LDS16(ksrc + (size_t)k1 * 3072, &Ks[nb][tid * 8]);
            GL2LDS16(ksrc + (size_t)(k1 + 32) * 3072, &Ks[nb][tid * 8 + 2048]);
            GL2LDS16(vsrc + k1, &Vts[nb][tid * 8]);
            GL2LDS16(vsrc + k1 + 32 * 2048, &Vts[nb][tid * 8 + 2048]);
            SYNC_VM(4);
        } else {
            SYNC_VM(0);
        }

        if (c < mynch) {
            const u16* Kb = Ks[c & 1];
            const u16* Vb = Vts[c & 1];

            // ---- S^T = K Q^T (rows = pi-permuted keys) ----
            f32x4 s[4];
            __builtin_amdgcn_s_setprio(1);
#pragma unroll
            for (int kt = 0; kt < 4; ++kt) {
                const u16* kr = Kb + (kt * 16 + ln) * 64;
                bf16x8 kf0 = *(const bf16x8*)(kr + ((qd ^ swz) * 8));
                bf16x8 kf1 = *(const bf16x8*)(kr + (((qd + 4) ^ swz) * 8));
                f32x4 z = {0.f, 0.f, 0.f, 0.f};
                z = __builtin_amdgcn_mfma_f32_16x16x32_bf16(kf0, qf0, z, 0, 0, 0);
                z = __builtin_amdgcn_mfma_f32_16x16x32_bf16(kf1, qf1, z, 0, 0, 0);
                s[kt] = z;
            }
            __builtin_amdgcn_s_setprio(0);

            // ---- causal mask (diagonal chunk only), permuted key identity ----
            if (c == mynch - 1) {
#pragma unroll
                for (int kt = 0; kt < 4; ++kt)
#pragma unroll
                    for (int r = 0; r < 4; ++r) {
                        int key = c * 64 + 32 * (kt >> 1) + 8 * qd + 4 * (kt & 1) + r;
                        if (key > myq) s[kt][r] = -1e30f;
                    }
            }

            // ---- exp2 + pack DIRECTLY into PV B-frags (zero LDS / cross-lane) ----
            bf16x8 pf0, pf1;
#pragma unroll
            for (int kt = 0; kt < 4; ++kt)
#pragma unroll
                for (int r = 0; r < 4; ++r) {
                    float p = fast_exp2(s[kt][r]);
                    l += p;
                    if (kt < 2) pf0[(kt & 1) * 4 + r] = (__bf16)p;
                    else        pf1[(kt & 1) * 4 + r] = (__bf16)p;
                }

            // ---- PV (V natural key order) ----
            __builtin_amdgcn_s_setprio(1);
#pragma unroll
            for (int dt = 0; dt < 4; ++dt) {
                const u16* vr = Vb + (dt * 16 + ln) * 64;
                bf16x8 vf0 = *(const bf16x8*)(vr + ((qd ^ swz) * 8));
                bf16x8 vf1 = *(const bf16x8*)(vr + (((qd + 4) ^ swz) * 8));
                o[dt] = __builtin_amdgcn_mfma_f32_16x16x32_bf16(vf0, pf0, o[dt], 0, 0, 0);
                o[dt] = __builtin_amdgcn_mfma_f32_16x16x32_bf16(vf1, pf1, o[dt], 0, 0, 0);
            }
            __builtin_amdgcn_s_setprio(0);
        }
        BAR();
    }

    // ---- deferred l reduction, normalize, packed stores ----
    l += __shfl_xor(l, 16); l += __shfl_xor(l, 32);
    float inv = 1.0f / l;
#pragma unroll
    for (int dt = 0; dt < 4; ++dt) {
        uint2 ov = {pack2bf(o[dt][0] * inv, o[dt][1] * inv),
                    pack2bf(o[dt][2] * inv, o[dt][3] * inv)};
        *(uint2*)&AO[(size_t)(b * 2048 + myq) * 1024 + h * 64 + dt * 16 + qd * 4] = ov;
    }
}

// ---------- launch ----------
extern "C" void kernel_launch(void* const* d_in, const int* in_sizes, int n_in,
                              void* d_out, int out_size, void* d_ws, size_t ws_size,
                              hipStream_t stream) {
    const float* x   = (const float*)d_in[0];   // [2,2048,1024]
    const float* qkv = (const float*)d_in[1];   // [3072,1024]
    const float* wo  = (const float*)d_in[2];   // [1024,1024]
    float* out = (float*)d_out;                 // [2,2048,1024] fp32

    char* ws = (char*)d_ws;
    u16* xb    = (u16*)(ws + 0);            //  8 MB : x bf16 [4096,1024]
    u16* qkvb  = (u16*)(ws + 8388608);      //  6 MB : qkv bf16 [3072,1024]
    u16* wob   = (u16*)(ws + 14680064);     //  2 MB : wo bf16 [1024,1024]
    u16* QKVo  = (u16*)(ws + 16777216);     // 24 MB : QKV bf16 (V-cols unwritten)
    u16* AO    = (u16*)(ws + 41943040);     //  8 MB : attn out [4096,1024]
    u16* VtG   = (u16*)(ws + 50331648);     //  8 MB : V^T [2*16*64, 2048]

    convert_all_kernel<<<8192, 256, 0, stream>>>(x, qkv, wo, xb);

    gemm_bt<128, true, true><<<dim3(24, 32), 256, 0, stream>>>(xb, qkvb, QKVo, VtG,
                                                               4096, 3072, 1024);

    attn_kernel<<<dim3(32, 16, 2), 256, 0, stream>>>(QKVo, VtG, AO);

    gemm_bt<64, false, false><<<dim3(8, 64), 256, 0, stream>>>(AO, wob, out, nullptr,
                                                               4096, 1024, 1024);
}